// Round 8
// baseline (307.156 us; speedup 1.0000x reference)
//
#include <hip/hip_runtime.h>
#include <hip/hip_bf16.h>

typedef __attribute__((ext_vector_type(8))) short sh8;        // 8 x bf16 bits (4 VGPR)
typedef __attribute__((ext_vector_type(16))) float fx16;      // MFMA 32x32 accumulator
typedef __attribute__((ext_vector_type(4))) unsigned int u32x4;

__device__ __forceinline__ unsigned short f2bits(float a) {
  union { __hip_bfloat16 h; unsigned short u; } c;
  c.h = __float2bfloat16(a);
  return c.u;
}
// one-instruction RNE pack: lo = cvt(a), hi = cvt(b)
__device__ __forceinline__ unsigned int pkcvt(float a, float b) {
  unsigned int r;
  asm("v_cvt_pk_bf16_f32 %0, %1, %2" : "=v"(r) : "v"(a), "v"(b));
  return r;
}
__device__ __forceinline__ fx16 fzero16() {
  fx16 z;
  #pragma unroll
  for (int i = 0; i < 16; ++i) z[i] = 0.0f;
  return z;
}

// ---------------------------------------------------------------------------
// Kernel 1: batched Cayley transform Q = (I-A)(I+A)^-1 for P1 (64) and P2 (64).
// ---------------------------------------------------------------------------
__global__ void k_cayley(const float* __restrict__ P1, const float* __restrict__ P2,
                         float* __restrict__ Qout) {
  int t = blockIdx.x * blockDim.x + threadIdx.x;
  int mat = t >> 4;
  int row = t & 15;
  if (mat >= 128) return;
  const float* P = (mat < 64) ? (P1 + mat * 256) : (P2 + (mat - 64) * 256);
  float M[16], Rr[16];
  #pragma unroll
  for (int j = 0; j < 16; ++j) {
    float a = 0.0f;
    if (j > row) a = P[row * 16 + j];
    if (j < row) a = -P[j * 16 + row];
    float d = (j == row) ? 1.0f : 0.0f;
    M[j]  = d + a;
    Rr[j] = d - a;
  }
  int gbase = (threadIdx.x & 63) & ~15;
  #pragma unroll
  for (int k = 0; k < 16; ++k) {
    float pkk = __shfl(M[k], gbase + k);
    float inv = 1.0f / pkk;
    float pM[16], pR[16];
    #pragma unroll
    for (int j = 0; j < 16; ++j) {
      pM[j] = __shfl(M[j], gbase + k) * inv;
      pR[j] = __shfl(Rr[j], gbase + k) * inv;
    }
    if (row == k) {
      #pragma unroll
      for (int j = 0; j < 16; ++j) { M[j] = pM[j]; Rr[j] = pR[j]; }
    } else {
      float f = M[k];
      #pragma unroll
      for (int j = 0; j < 16; ++j) { M[j] -= f * pM[j]; Rr[j] -= f * pR[j]; }
    }
  }
  float* qo = Qout + mat * 256 + row * 16;
  #pragma unroll
  for (int j = 0; j < 16; ++j) qo[j] = Rr[j];
}

// ---------------------------------------------------------------------------
// Kernel 2: build folded weights in bf16, MFMA B-fragment order.
// W1[t2][tile(2)][kstep(4)][lane(64)][r(8)]: k-map q = kstep*16 + 8h + r.
// W2[t2][tile(2)][kstep(4)][lane(64)][r(8)]: k-map s = kstep*16 + sigma(h,r),
//   sigma(h,r) = (r&3) + 8*(r>>2) + 4h  -- so GEMM2's A-frag is accY regs
//   in order after v_cvt_pk (no cross-lane permute).
// ---------------------------------------------------------------------------
__global__ void k_build(const float* __restrict__ P0, const float* __restrict__ P3,
                        const float* __restrict__ Qbuf,
                        unsigned short* __restrict__ W1, unsigned short* __restrict__ W2) {
  int t = blockIdx.x * blockDim.x + threadIdx.x;
  if (t >= 131072) return;
  const float* Q1 = Qbuf;
  const float* Q2 = Qbuf + 16384;
  int e  = t & 65535;
  int r  = e & 7;
  int l  = (e >> 3) & 63;
  int kx = (e >> 9) & 3;
  int mt = (e >> 11) & 1;
  int t2 = (e >> 12) & 15;
  float acc = 0.0f;
  if (t < 65536) {
    int m = mt * 32 + (l & 31);
    int q = kx * 16 + ((l >> 5) << 3) + r;
    int j0 = m >> 3, j1 = m & 7, i0 = q >> 3, i1 = q & 7;
    #pragma unroll
    for (int t1 = 0; t1 < 16; ++t1) {
      float c0 = P0[(j0 * 8 + (t1 >> 1)) * 16 + ((t1 & 1) * 8 + i0)];
      int a1 = j1 * 16 + t2, u1 = t1 * 8 + i1;
      float c1 = Q1[((a1 & 7) * 8 + (u1 >> 4)) * 256 + (a1 >> 3) * 16 + (u1 & 15)];
      acc += c0 * c1;
    }
    W1[e] = f2bits(acc);
  } else {
    int n = mt * 32 + (l & 31);
    int s = kx * 16 + (r & 3) + 8 * (r >> 2) + 4 * (l >> 5);   // sigma-permuted k-map
    int j2 = n >> 3, j3 = n & 7, i2 = s >> 3, i3 = s & 7;
    #pragma unroll
    for (int t3 = 0; t3 < 16; ++t3) {
      int a2 = j2 * 16 + t3, u2 = t2 * 8 + i2;
      float c2 = Q2[((a2 & 7) * 8 + (u2 >> 4)) * 256 + (a2 >> 3) * 16 + (u2 & 15)];
      float c3 = P3[((t3 & 7) * 8 + i3) * 16 + (j3 * 2 + (t3 >> 3))];
      acc += c2 * c3;
    }
    W2[e] = f2bits(acc);
  }
}

// ---------------------------------------------------------------------------
// Kernel 3 (R3 structure revived + R6/R7 fixes). WG = 4 waves / 2 batch elems.
// Wave w: elem ep = w>>1, m-half mh = w&1. Per t2: 16 MFMA (8 GEMM1 + 8 GEMM2)
// -- small per-wave stream, but 4 waves/SIMD of independent streams keep the
// MFMA pipe fed (launch_bounds(256,4); total regs ~124 per R3 evidence).
// Pack = 8x v_cvt_pk (sigma in W2, no permute). No t2 stagger (L1-resident
// 12 KB weight slice shared by all waves). b1 reloaded mid-iter; b2 issued
// between GEMM1 and pack (latency under GEMM1 drain + TLP).
// ---------------------------------------------------------------------------
__global__ __launch_bounds__(256, 4) void k_main(
    const float* __restrict__ x,
    const unsigned short* __restrict__ W1,
    const unsigned short* __restrict__ W2,
    const float* __restrict__ bias,
    float* __restrict__ out) {
  __shared__ __align__(16) char XsT[2 * 8192];   // [elem][64 s][128 B], swizzled

  const int tid  = threadIdx.x;
  const int lane = tid & 63;
  const int w    = tid >> 6;
  const int h    = lane >> 5;
  const int l31  = lane & 31;
  const int ep   = w >> 1;         // elem this wave works on
  const int mh   = w & 1;          // m-half this wave owns
  const size_t bbase = (size_t)blockIdx.x * 2;

  // ---- Cooperative stage of both X elems (f32 -> bf16, [s][q], swizzled) ----
  {
    const int e  = tid >> 7;          // elem staged by this thread
    const int s  = tid & 63;
    const int qh = (tid >> 6) & 1;    // q-half
    const float* xb = x + (bbase + e) * 4096;
    const unsigned sw = ((unsigned)(s & 7)) << 4;
    char* base = XsT + e * 8192 + s * 128;
    #pragma unroll
    for (int c = 0; c < 2; ++c) {     // 16 q per chunk
      int qb = qh * 32 + c * 16;
      unsigned int d[8];
      #pragma unroll
      for (int jj = 0; jj < 8; ++jj) {
        float a  = xb[(qb + 2 * jj + 0) * 64 + s];
        float bq = xb[(qb + 2 * jj + 1) * 64 + s];
        d[jj] = pkcvt(a, bq);
      }
      u32x4 v0 = {d[0], d[1], d[2], d[3]};
      u32x4 v1 = {d[4], d[5], d[6], d[7]};
      *(u32x4*)(base + (((unsigned)(qb * 2)) ^ sw))      = v0;
      *(u32x4*)(base + (((unsigned)(qb * 2 + 16)) ^ sw)) = v1;
    }
  }
  __syncthreads();

  // ---- Hoist GEMM1 A-frags (loop-invariant): 8 x ds_read_b128 ----
  const char* myX = XsT + ep * 8192;
  sh8 af[2][4];
  #pragma unroll
  for (int st = 0; st < 2; ++st)
    #pragma unroll
    for (int kq = 0; kq < 4; ++kq) {
      int srow = st * 32 + l31;
      unsigned boff = (unsigned)srow * 128 +
                      (((unsigned)(kq * 32 + h * 16)) ^ (((unsigned)(srow & 7)) << 4));
      af[st][kq] = *(const sh8*)(myX + boff);
    }

  const fx16 zc = fzero16();
  fx16 accO[2];                    // [nt]
  accO[0] = zc; accO[1] = zc;

  const sh8* w1f = (const sh8*)W1;   // idx: t2*512 + (tile*4+kstep)*64 + lane
  const sh8* w2f = (const sh8*)W2;

  // ---- prologue: b1 for t2=0 (single-buffered, reloaded mid-iteration) ----
  sh8 b1[4];
  #pragma unroll
  for (int kq = 0; kq < 4; ++kq)
    b1[kq] = w1f[(mh * 4 + kq) * 64 + lane];

  #pragma unroll 1
  for (int t2 = 0; t2 < 16; ++t2) {
    // ---- GEMM1: Y^T(s, mh-half): 8 MFMA, 2 st-chains ----
    fx16 accY[2];
    __builtin_amdgcn_s_setprio(1);
    accY[0] = __builtin_amdgcn_mfma_f32_32x32x16_bf16(af[0][0], b1[0], zc, 0, 0, 0);
    accY[1] = __builtin_amdgcn_mfma_f32_32x32x16_bf16(af[1][0], b1[0], zc, 0, 0, 0);
    #pragma unroll
    for (int kq = 1; kq < 4; ++kq) {
      accY[0] = __builtin_amdgcn_mfma_f32_32x32x16_bf16(af[0][kq], b1[kq], accY[0], 0, 0, 0);
      accY[1] = __builtin_amdgcn_mfma_f32_32x32x16_bf16(af[1][kq], b1[kq], accY[1], 0, 0, 0);
    }
    __builtin_amdgcn_s_setprio(0);

    // ---- b2 block issue (consumed after pack; latency under GEMM1 drain) ----
    sh8 b2[2][4];
    #pragma unroll
    for (int nt = 0; nt < 2; ++nt)
      #pragma unroll
      for (int ks = 0; ks < 4; ++ks)
        b2[nt][ks] = w2f[t2 * 512 + (nt * 4 + ks) * 64 + lane];

    // ---- reload b1 for t2+1 (WAR after GEMM1; covered by GEMM2) ----
    {
      const int t2n = (t2 + 1) & 15;
      #pragma unroll
      for (int kq = 0; kq < 4; ++kq)
        b1[kq] = w1f[t2n * 512 + (mh * 4 + kq) * 64 + lane];
    }

    // ---- pack: 16x cvt_pk, regs in order (sigma in W2) ----
    sh8 ga[4];
    #pragma unroll
    for (int st = 0; st < 2; ++st) {
      fx16 Y = accY[st];
      union { u32x4 u; sh8 s8; } c0, c1;
      c0.u = (u32x4){pkcvt(Y[0], Y[1]),  pkcvt(Y[2], Y[3]),
                     pkcvt(Y[4], Y[5]),  pkcvt(Y[6], Y[7])};
      c1.u = (u32x4){pkcvt(Y[8], Y[9]),  pkcvt(Y[10], Y[11]),
                     pkcvt(Y[12], Y[13]), pkcvt(Y[14], Y[15])};
      ga[st * 2 + 0] = c0.s8;
      ga[st * 2 + 1] = c1.s8;
    }

    // ---- GEMM2: out[mh,:] += Y @ B23_t2: 8 MFMA, 2 nt-chains ----
    __builtin_amdgcn_s_setprio(1);
    #pragma unroll
    for (int ks = 0; ks < 4; ++ks) {
      accO[0] = __builtin_amdgcn_mfma_f32_32x32x16_bf16(ga[ks], b2[0][ks], accO[0], 0, 0, 0);
      accO[1] = __builtin_amdgcn_mfma_f32_32x32x16_bf16(ga[ks], b2[1][ks], accO[1], 0, 0, 0);
    }
    __builtin_amdgcn_s_setprio(0);
  }

  // ---- epilogue: out[b][m*64+n] = acc + bias ----
  float* ob = out + (bbase + ep) * 4096;
  #pragma unroll
  for (int nt = 0; nt < 2; ++nt) {
    #pragma unroll
    for (int reg = 0; reg < 16; ++reg) {
      int m = mh * 32 + (reg & 3) + 8 * (reg >> 2) + 4 * h;
      int n = nt * 32 + l31;
      int o = m * 64 + n;
      ob[o] = accO[nt][reg] + bias[o];
    }
  }
}

// ---------------------------------------------------------------------------
extern "C" void kernel_launch(void* const* d_in, const int* in_sizes, int n_in,
                              void* d_out, int out_size, void* d_ws, size_t ws_size,
                              hipStream_t stream) {
  (void)n_in; (void)out_size; (void)ws_size;
  const float* x    = (const float*)d_in[0];
  const float* P0   = (const float*)d_in[1];
  const float* P1   = (const float*)d_in[2];
  const float* P2   = (const float*)d_in[3];
  const float* P3   = (const float*)d_in[4];
  const float* bias = (const float*)d_in[5];
  float* out = (float*)d_out;

  // ws: Qbuf f32[128*256] (128 KB) | W1 bf16[65536] (128 KB) | W2 bf16[65536] (128 KB)
  float* Qbuf = (float*)d_ws;
  unsigned short* W1 = (unsigned short*)((char*)d_ws + 131072);
  unsigned short* W2 = (unsigned short*)((char*)d_ws + 262144);

  k_cayley<<<8, 256, 0, stream>>>(P1, P2, Qbuf);
  k_build<<<512, 256, 0, stream>>>(P0, P3, Qbuf, W1, W2);

  int batch = in_sizes[0] / 4096;
  k_main<<<batch / 2, 256, 0, stream>>>(x, W1, W2, bias, out);
}

// Round 9
// 138.994 us; speedup vs baseline: 2.2099x; 2.2099x over previous
//
#include <hip/hip_runtime.h>
#include <hip/hip_bf16.h>

typedef __attribute__((ext_vector_type(8))) short sh8;        // 8 x bf16 bits (4 VGPR)
typedef __attribute__((ext_vector_type(16))) float fx16;      // MFMA 32x32 accumulator
typedef __attribute__((ext_vector_type(4))) unsigned int u32x4;

__device__ __forceinline__ unsigned short f2bits(float a) {
  union { __hip_bfloat16 h; unsigned short u; } c;
  c.h = __float2bfloat16(a);
  return c.u;
}
// one-instruction RNE pack: lo = cvt(a), hi = cvt(b)
__device__ __forceinline__ unsigned int pkcvt(float a, float b) {
  unsigned int r;
  asm("v_cvt_pk_bf16_f32 %0, %1, %2" : "=v"(r) : "v"(a), "v"(b));
  return r;
}
__device__ __forceinline__ fx16 fzero16() {
  fx16 z;
  #pragma unroll
  for (int i = 0; i < 16; ++i) z[i] = 0.0f;
  return z;
}

// ---------------------------------------------------------------------------
// Kernel 1: batched Cayley transform Q = (I-A)(I+A)^-1 for P1 (64) and P2 (64).
// ---------------------------------------------------------------------------
__global__ void k_cayley(const float* __restrict__ P1, const float* __restrict__ P2,
                         float* __restrict__ Qout) {
  int t = blockIdx.x * blockDim.x + threadIdx.x;
  int mat = t >> 4;
  int row = t & 15;
  if (mat >= 128) return;
  const float* P = (mat < 64) ? (P1 + mat * 256) : (P2 + (mat - 64) * 256);
  float M[16], Rr[16];
  #pragma unroll
  for (int j = 0; j < 16; ++j) {
    float a = 0.0f;
    if (j > row) a = P[row * 16 + j];
    if (j < row) a = -P[j * 16 + row];
    float d = (j == row) ? 1.0f : 0.0f;
    M[j]  = d + a;
    Rr[j] = d - a;
  }
  int gbase = (threadIdx.x & 63) & ~15;
  #pragma unroll
  for (int k = 0; k < 16; ++k) {
    float pkk = __shfl(M[k], gbase + k);
    float inv = 1.0f / pkk;
    float pM[16], pR[16];
    #pragma unroll
    for (int j = 0; j < 16; ++j) {
      pM[j] = __shfl(M[j], gbase + k) * inv;
      pR[j] = __shfl(Rr[j], gbase + k) * inv;
    }
    if (row == k) {
      #pragma unroll
      for (int j = 0; j < 16; ++j) { M[j] = pM[j]; Rr[j] = pR[j]; }
    } else {
      float f = M[k];
      #pragma unroll
      for (int j = 0; j < 16; ++j) { M[j] -= f * pM[j]; Rr[j] -= f * pR[j]; }
    }
  }
  float* qo = Qout + mat * 256 + row * 16;
  #pragma unroll
  for (int j = 0; j < 16; ++j) qo[j] = Rr[j];
}

// ---------------------------------------------------------------------------
// Kernel 2: build folded weights in bf16, MFMA B-fragment order.
// W1[t2][tile(2)][kstep(4)][lane(64)][r(8)]: k-map q = kstep*16 + 8h + r.
// W2[t2][tile(2)][kstep(4)][lane(64)][r(8)]: k-map s = kstep*16 + sigma(h,r),
//   sigma(h,r) = (r&3) + 8*(r>>2) + 4h  -- so GEMM2's A-frag is accY regs
//   in order after v_cvt_pk (no cross-lane permute).
// ---------------------------------------------------------------------------
__global__ void k_build(const float* __restrict__ P0, const float* __restrict__ P3,
                        const float* __restrict__ Qbuf,
                        unsigned short* __restrict__ W1, unsigned short* __restrict__ W2) {
  int t = blockIdx.x * blockDim.x + threadIdx.x;
  if (t >= 131072) return;
  const float* Q1 = Qbuf;
  const float* Q2 = Qbuf + 16384;
  int e  = t & 65535;
  int r  = e & 7;
  int l  = (e >> 3) & 63;
  int kx = (e >> 9) & 3;
  int mt = (e >> 11) & 1;
  int t2 = (e >> 12) & 15;
  float acc = 0.0f;
  if (t < 65536) {
    int m = mt * 32 + (l & 31);
    int q = kx * 16 + ((l >> 5) << 3) + r;
    int j0 = m >> 3, j1 = m & 7, i0 = q >> 3, i1 = q & 7;
    #pragma unroll
    for (int t1 = 0; t1 < 16; ++t1) {
      float c0 = P0[(j0 * 8 + (t1 >> 1)) * 16 + ((t1 & 1) * 8 + i0)];
      int a1 = j1 * 16 + t2, u1 = t1 * 8 + i1;
      float c1 = Q1[((a1 & 7) * 8 + (u1 >> 4)) * 256 + (a1 >> 3) * 16 + (u1 & 15)];
      acc += c0 * c1;
    }
    W1[e] = f2bits(acc);
  } else {
    int n = mt * 32 + (l & 31);
    int s = kx * 16 + (r & 3) + 8 * (r >> 2) + 4 * (l >> 5);   // sigma-permuted k-map
    int j2 = n >> 3, j3 = n & 7, i2 = s >> 3, i3 = s & 7;
    #pragma unroll
    for (int t3 = 0; t3 < 16; ++t3) {
      int a2 = j2 * 16 + t3, u2 = t2 * 8 + i2;
      float c2 = Q2[((a2 & 7) * 8 + (u2 >> 4)) * 256 + (a2 >> 3) * 16 + (u2 & 15)];
      float c3 = P3[((t3 & 7) * 8 + i3) * 16 + (j3 * 2 + (t3 >> 3))];
      acc += c2 * c3;
    }
    W2[e] = f2bits(acc);
  }
}

// ---------------------------------------------------------------------------
// Kernel 3 (R7 compute + LDS-staged weights, T3 minimum-2-phase). WG = 4 waves
// / 4 batch elems; wave = (elem-pair, m-half). Per t2: issue next slice's
// 16 global_load_lds (dbuf), 12 ds_read_b128 weight frags from current slice,
// 32 MFMA (2 elems x {GEMM1,pack,GEMM2}), vmcnt(0)+barrier at iter end only.
// Weight bytes traverse VMEM once per WG (16 KB) instead of 48 KB of
// per-wave buffer_loads; delivery is on the LDS pipe. 2 WGs/CU anti-phase.
// ---------------------------------------------------------------------------
__global__ __launch_bounds__(256, 2) void k_main(
    const float* __restrict__ x,
    const unsigned short* __restrict__ W1,
    const unsigned short* __restrict__ W2,
    const float* __restrict__ bias,
    float* __restrict__ out) {
  __shared__ __align__(16) char smem[4 * 8192 + 2 * 16384];
  char* XsT = smem;                 // [elem][64 s][128 B], swizzled
  char* WL  = smem + 32768;         // [2][16384]: dbuf weight slice (W1|W2)

  const int tid  = threadIdx.x;
  const int lane = tid & 63;
  const int w    = tid >> 6;
  const int h    = lane >> 5;
  const int l31  = lane & 31;
  const int ep   = (w >> 1) * 2;    // first elem of this wave's pair
  const int mh   = w & 1;           // m-half this wave owns
  const size_t bbase = (size_t)blockIdx.x * 4;

  const char* w1c = (const char*)W1;
  const char* w2c = (const char*)W2;

  // ---- issue weight stage for t2=0 first (DMA overlaps X staging) ----
  {
    char* dst = WL;                               // buffer 0
    #pragma unroll
    for (int c = 0; c < 4; ++c) {
      const char* src = (c < 2) ? (w1c + c * 4096) : (w2c + (c - 2) * 4096);
      src += w * 1024 + lane * 16;
      __builtin_amdgcn_global_load_lds((const unsigned int*)src,
                                       (unsigned int*)(dst + c * 4096 + w * 1024),
                                       16, 0, 0);
    }
  }

  // ---- Wave w stages elem w (f32 -> bf16, [s][q] transposed, swizzled) ----
  {
    const int s = lane;
    const float* xb = x + (bbase + w) * 4096;
    const unsigned sw = ((unsigned)(s & 7)) << 4;
    char* base = XsT + w * 8192 + s * 128;
    #pragma unroll
    for (int c = 0; c < 4; ++c) {               // 16 q per chunk
      unsigned int d[8];
      #pragma unroll
      for (int jj = 0; jj < 8; ++jj) {
        float a  = xb[(c * 16 + 2 * jj + 0) * 64 + s];
        float bq = xb[(c * 16 + 2 * jj + 1) * 64 + s];
        d[jj] = pkcvt(a, bq);
      }
      u32x4 v0 = {d[0], d[1], d[2], d[3]};
      u32x4 v1 = {d[4], d[5], d[6], d[7]};
      *(u32x4*)(base + (((unsigned)(c * 32)) ^ sw))      = v0;
      *(u32x4*)(base + (((unsigned)(c * 32 + 16)) ^ sw)) = v1;
    }
  }
  asm volatile("s_waitcnt vmcnt(0)" ::: "memory");
  __syncthreads();

  // ---- Hoist GEMM1 A-frags for both elems (loop-invariant): 16 ds_read_b128
  sh8 af[2][2][4];
  #pragma unroll
  for (int e = 0; e < 2; ++e) {
    const char* myX = XsT + (ep + e) * 8192;
    #pragma unroll
    for (int st = 0; st < 2; ++st)
      #pragma unroll
      for (int kq = 0; kq < 4; ++kq) {
        int srow = st * 32 + l31;
        unsigned boff = (unsigned)srow * 128 +
                        (((unsigned)(kq * 32 + h * 16)) ^ (((unsigned)(srow & 7)) << 4));
        af[e][st][kq] = *(const sh8*)(myX + boff);
      }
  }

  const fx16 zc = fzero16();
  fx16 accO[2][2];                 // [elem][nt]
  accO[0][0] = zc; accO[0][1] = zc;
  accO[1][0] = zc; accO[1][1] = zc;

  #pragma unroll 1
  for (int t2 = 0; t2 < 16; ++t2) {
    char* cur = WL + (t2 & 1) * 16384;

    // ---- issue stage of t2+1 into the other buffer (landed-by-barrier) ----
    if (t2 < 15) {
      char* dst = WL + ((t2 + 1) & 1) * 16384;
      const size_t toff = (size_t)(t2 + 1) * 8192;
      #pragma unroll
      for (int c = 0; c < 4; ++c) {
        const char* src = (c < 2) ? (w1c + toff + c * 4096)
                                  : (w2c + toff + (c - 2) * 4096);
        src += w * 1024 + lane * 16;
        __builtin_amdgcn_global_load_lds((const unsigned int*)src,
                                         (unsigned int*)(dst + c * 4096 + w * 1024),
                                         16, 0, 0);
      }
    }

    // ---- weight frags from LDS (12 ds_read_b128, canonical pattern) ----
    sh8 b1[4];
    #pragma unroll
    for (int kq = 0; kq < 4; ++kq)
      b1[kq] = *(const sh8*)(cur + (((mh * 4 + kq) * 64 + lane) << 4));
    sh8 b2[2][4];
    #pragma unroll
    for (int nt = 0; nt < 2; ++nt)
      #pragma unroll
      for (int ks = 0; ks < 4; ++ks)
        b2[nt][ks] = *(const sh8*)(cur + 8192 + (((nt * 4 + ks) * 64 + lane) << 4));

    // ---- GEMM1 elem0: 8 MFMA, 2 st-chains ----
    fx16 accY[2];
    __builtin_amdgcn_s_setprio(1);
    accY[0] = __builtin_amdgcn_mfma_f32_32x32x16_bf16(af[0][0][0], b1[0], zc, 0, 0, 0);
    accY[1] = __builtin_amdgcn_mfma_f32_32x32x16_bf16(af[0][1][0], b1[0], zc, 0, 0, 0);
    #pragma unroll
    for (int kq = 1; kq < 4; ++kq) {
      accY[0] = __builtin_amdgcn_mfma_f32_32x32x16_bf16(af[0][0][kq], b1[kq], accY[0], 0, 0, 0);
      accY[1] = __builtin_amdgcn_mfma_f32_32x32x16_bf16(af[0][1][kq], b1[kq], accY[1], 0, 0, 0);
    }
    __builtin_amdgcn_s_setprio(0);

    // ---- pack elem0 -> ga0 (16x cvt_pk; sigma in W2) ----
    sh8 ga0[4];
    #pragma unroll
    for (int st = 0; st < 2; ++st) {
      fx16 Y = accY[st];
      union { u32x4 u; sh8 s8; } c0, c1;
      c0.u = (u32x4){pkcvt(Y[0], Y[1]),  pkcvt(Y[2], Y[3]),
                     pkcvt(Y[4], Y[5]),  pkcvt(Y[6], Y[7])};
      c1.u = (u32x4){pkcvt(Y[8], Y[9]),  pkcvt(Y[10], Y[11]),
                     pkcvt(Y[12], Y[13]), pkcvt(Y[14], Y[15])};
      ga0[st * 2 + 0] = c0.s8;
      ga0[st * 2 + 1] = c1.s8;
    }

    // ---- GEMM1 elem1 ----
    fx16 accZ[2];
    __builtin_amdgcn_s_setprio(1);
    accZ[0] = __builtin_amdgcn_mfma_f32_32x32x16_bf16(af[1][0][0], b1[0], zc, 0, 0, 0);
    accZ[1] = __builtin_amdgcn_mfma_f32_32x32x16_bf16(af[1][1][0], b1[0], zc, 0, 0, 0);
    #pragma unroll
    for (int kq = 1; kq < 4; ++kq) {
      accZ[0] = __builtin_amdgcn_mfma_f32_32x32x16_bf16(af[1][0][kq], b1[kq], accZ[0], 0, 0, 0);
      accZ[1] = __builtin_amdgcn_mfma_f32_32x32x16_bf16(af[1][1][kq], b1[kq], accZ[1], 0, 0, 0);
    }

    // ---- GEMM2 elem0 (hides elem1's chain drain) ----
    #pragma unroll
    for (int ks = 0; ks < 4; ++ks) {
      accO[0][0] = __builtin_amdgcn_mfma_f32_32x32x16_bf16(ga0[ks], b2[0][ks], accO[0][0], 0, 0, 0);
      accO[0][1] = __builtin_amdgcn_mfma_f32_32x32x16_bf16(ga0[ks], b2[1][ks], accO[0][1], 0, 0, 0);
    }
    __builtin_amdgcn_s_setprio(0);

    // ---- pack elem1 -> ga1 ----
    sh8 ga1[4];
    #pragma unroll
    for (int st = 0; st < 2; ++st) {
      fx16 Y = accZ[st];
      union { u32x4 u; sh8 s8; } c0, c1;
      c0.u = (u32x4){pkcvt(Y[0], Y[1]),  pkcvt(Y[2], Y[3]),
                     pkcvt(Y[4], Y[5]),  pkcvt(Y[6], Y[7])};
      c1.u = (u32x4){pkcvt(Y[8], Y[9]),  pkcvt(Y[10], Y[11]),
                     pkcvt(Y[12], Y[13]), pkcvt(Y[14], Y[15])};
      ga1[st * 2 + 0] = c0.s8;
      ga1[st * 2 + 1] = c1.s8;
    }

    // ---- GEMM2 elem1 ----
    __builtin_amdgcn_s_setprio(1);
    #pragma unroll
    for (int ks = 0; ks < 4; ++ks) {
      accO[1][0] = __builtin_amdgcn_mfma_f32_32x32x16_bf16(ga1[ks], b2[0][ks], accO[1][0], 0, 0, 0);
      accO[1][1] = __builtin_amdgcn_mfma_f32_32x32x16_bf16(ga1[ks], b2[1][ks], accO[1][1], 0, 0, 0);
    }
    __builtin_amdgcn_s_setprio(0);

    // ---- single per-iter sync: stage landed, all reads of cur done ----
    asm volatile("s_waitcnt vmcnt(0)" ::: "memory");
    __syncthreads();
  }

  // ---- epilogue ----
  #pragma unroll
  for (int e = 0; e < 2; ++e) {
    float* ob = out + (bbase + ep + e) * 4096;
    #pragma unroll
    for (int nt = 0; nt < 2; ++nt) {
      #pragma unroll
      for (int reg = 0; reg < 16; ++reg) {
        int m = mh * 32 + (reg & 3) + 8 * (reg >> 2) + 4 * h;
        int n = nt * 32 + l31;
        int o = m * 64 + n;
        ob[o] = accO[e][nt][reg] + bias[o];
      }
    }
  }
}

// ---------------------------------------------------------------------------
extern "C" void kernel_launch(void* const* d_in, const int* in_sizes, int n_in,
                              void* d_out, int out_size, void* d_ws, size_t ws_size,
                              hipStream_t stream) {
  (void)n_in; (void)out_size; (void)ws_size;
  const float* x    = (const float*)d_in[0];
  const float* P0   = (const float*)d_in[1];
  const float* P1   = (const float*)d_in[2];
  const float* P2   = (const float*)d_in[3];
  const float* P3   = (const float*)d_in[4];
  const float* bias = (const float*)d_in[5];
  float* out = (float*)d_out;

  // ws: Qbuf f32[128*256] (128 KB) | W1 bf16[65536] (128 KB) | W2 bf16[65536] (128 KB)
  float* Qbuf = (float*)d_ws;
  unsigned short* W1 = (unsigned short*)((char*)d_ws + 131072);
  unsigned short* W2 = (unsigned short*)((char*)d_ws + 262144);

  k_cayley<<<8, 256, 0, stream>>>(P1, P2, Qbuf);
  k_build<<<512, 256, 0, stream>>>(P0, P3, Qbuf, W1, W2);

  int batch = in_sizes[0] / 4096;
  k_main<<<batch / 4, 256, 0, stream>>>(x, W1, W2, bias, out);
}

// Round 10
// 137.675 us; speedup vs baseline: 2.2310x; 1.0096x over previous
//
#include <hip/hip_runtime.h>
#include <hip/hip_bf16.h>

typedef __attribute__((ext_vector_type(8))) short sh8;        // 8 x bf16 bits (4 VGPR)
typedef __attribute__((ext_vector_type(16))) float fx16;      // MFMA 32x32 accumulator
typedef __attribute__((ext_vector_type(4))) unsigned int u32x4;

__device__ __forceinline__ unsigned short f2bits(float a) {
  union { __hip_bfloat16 h; unsigned short u; } c;
  c.h = __float2bfloat16(a);
  return c.u;
}
// one-instruction RNE pack: lo = cvt(a), hi = cvt(b)
__device__ __forceinline__ unsigned int pkcvt(float a, float b) {
  unsigned int r;
  asm("v_cvt_pk_bf16_f32 %0, %1, %2" : "=v"(r) : "v"(a), "v"(b));
  return r;
}
__device__ __forceinline__ fx16 fzero16() {
  fx16 z;
  #pragma unroll
  for (int i = 0; i < 16; ++i) z[i] = 0.0f;
  return z;
}

// ---------------------------------------------------------------------------
// Kernel 1: batched Cayley transform Q = (I-A)(I+A)^-1 for P1 (64) and P2 (64).
// ---------------------------------------------------------------------------
__global__ void k_cayley(const float* __restrict__ P1, const float* __restrict__ P2,
                         float* __restrict__ Qout) {
  int t = blockIdx.x * blockDim.x + threadIdx.x;
  int mat = t >> 4;
  int row = t & 15;
  if (mat >= 128) return;
  const float* P = (mat < 64) ? (P1 + mat * 256) : (P2 + (mat - 64) * 256);
  float M[16], Rr[16];
  #pragma unroll
  for (int j = 0; j < 16; ++j) {
    float a = 0.0f;
    if (j > row) a = P[row * 16 + j];
    if (j < row) a = -P[j * 16 + row];
    float d = (j == row) ? 1.0f : 0.0f;
    M[j]  = d + a;
    Rr[j] = d - a;
  }
  int gbase = (threadIdx.x & 63) & ~15;
  #pragma unroll
  for (int k = 0; k < 16; ++k) {
    float pkk = __shfl(M[k], gbase + k);
    float inv = 1.0f / pkk;
    float pM[16], pR[16];
    #pragma unroll
    for (int j = 0; j < 16; ++j) {
      pM[j] = __shfl(M[j], gbase + k) * inv;
      pR[j] = __shfl(Rr[j], gbase + k) * inv;
    }
    if (row == k) {
      #pragma unroll
      for (int j = 0; j < 16; ++j) { M[j] = pM[j]; Rr[j] = pR[j]; }
    } else {
      float f = M[k];
      #pragma unroll
      for (int j = 0; j < 16; ++j) { M[j] -= f * pM[j]; Rr[j] -= f * pR[j]; }
    }
  }
  float* qo = Qout + mat * 256 + row * 16;
  #pragma unroll
  for (int j = 0; j < 16; ++j) qo[j] = Rr[j];
}

// ---------------------------------------------------------------------------
// Kernel 2: build folded weights in bf16, MFMA B-fragment order.
// W1[t2][tile(2)][kstep(4)][lane(64)][r(8)]: k-map q = kstep*16 + 8h + r.
// W2[t2][tile(2)][kstep(4)][lane(64)][r(8)]: k-map s = kstep*16 + sigma(h,r),
//   sigma(h,r) = (r&3) + 8*(r>>2) + 4h  -- so GEMM2's A-frag is accY regs
//   in order after v_cvt_pk (no cross-lane permute).
// ---------------------------------------------------------------------------
__global__ void k_build(const float* __restrict__ P0, const float* __restrict__ P3,
                        const float* __restrict__ Qbuf,
                        unsigned short* __restrict__ W1, unsigned short* __restrict__ W2) {
  int t = blockIdx.x * blockDim.x + threadIdx.x;
  if (t >= 131072) return;
  const float* Q1 = Qbuf;
  const float* Q2 = Qbuf + 16384;
  int e  = t & 65535;
  int r  = e & 7;
  int l  = (e >> 3) & 63;
  int kx = (e >> 9) & 3;
  int mt = (e >> 11) & 1;
  int t2 = (e >> 12) & 15;
  float acc = 0.0f;
  if (t < 65536) {
    int m = mt * 32 + (l & 31);
    int q = kx * 16 + ((l >> 5) << 3) + r;
    int j0 = m >> 3, j1 = m & 7, i0 = q >> 3, i1 = q & 7;
    #pragma unroll
    for (int t1 = 0; t1 < 16; ++t1) {
      float c0 = P0[(j0 * 8 + (t1 >> 1)) * 16 + ((t1 & 1) * 8 + i0)];
      int a1 = j1 * 16 + t2, u1 = t1 * 8 + i1;
      float c1 = Q1[((a1 & 7) * 8 + (u1 >> 4)) * 256 + (a1 >> 3) * 16 + (u1 & 15)];
      acc += c0 * c1;
    }
    W1[e] = f2bits(acc);
  } else {
    int n = mt * 32 + (l & 31);
    int s = kx * 16 + (r & 3) + 8 * (r >> 2) + 4 * (l >> 5);   // sigma-permuted k-map
    int j2 = n >> 3, j3 = n & 7, i2 = s >> 3, i3 = s & 7;
    #pragma unroll
    for (int t3 = 0; t3 < 16; ++t3) {
      int a2 = j2 * 16 + t3, u2 = t2 * 8 + i2;
      float c2 = Q2[((a2 & 7) * 8 + (u2 >> 4)) * 256 + (a2 >> 3) * 16 + (u2 & 15)];
      float c3 = P3[((t3 & 7) * 8 + i3) * 16 + (j3 * 2 + (t3 >> 3))];
      acc += c2 * c3;
    }
    W2[e] = f2bits(acc);
  }
}

// ---------------------------------------------------------------------------
// Kernel 3 (R9 + 4-chain ILP merge). WG = 4 waves / 4 batch elems; wave =
// (elem-pair, m-half). Per t2: stage t2+1 (16 gload_lds, dbuf), 4 b1
// ds_reads, G1 MERGED (16 MFMA over 4 chains accY0,accY1,accZ0,accZ1 --
// same-chain reissue gap 128 cyc covers MFMA dep latency), 8 b2 ds_reads
// (latency under packs), both packs (32 cvt_pk), G2 MERGED (16 MFMA over 4
// accO chains), vmcnt(0)+barrier. 2 WGs/CU anti-phase.
// ---------------------------------------------------------------------------
__global__ __launch_bounds__(256, 2) void k_main(
    const float* __restrict__ x,
    const unsigned short* __restrict__ W1,
    const unsigned short* __restrict__ W2,
    const float* __restrict__ bias,
    float* __restrict__ out) {
  __shared__ __align__(16) char smem[4 * 8192 + 2 * 16384];
  char* XsT = smem;                 // [elem][64 s][128 B], swizzled
  char* WL  = smem + 32768;         // [2][16384]: dbuf weight slice (W1|W2)

  const int tid  = threadIdx.x;
  const int lane = tid & 63;
  const int w    = tid >> 6;
  const int h    = lane >> 5;
  const int l31  = lane & 31;
  const int ep   = (w >> 1) * 2;    // first elem of this wave's pair
  const int mh   = w & 1;           // m-half this wave owns
  const size_t bbase = (size_t)blockIdx.x * 4;

  const char* w1c = (const char*)W1;
  const char* w2c = (const char*)W2;

  // ---- issue weight stage for t2=0 first (DMA overlaps X staging) ----
  {
    char* dst = WL;                               // buffer 0
    #pragma unroll
    for (int c = 0; c < 4; ++c) {
      const char* src = (c < 2) ? (w1c + c * 4096) : (w2c + (c - 2) * 4096);
      src += w * 1024 + lane * 16;
      __builtin_amdgcn_global_load_lds((const unsigned int*)src,
                                       (unsigned int*)(dst + c * 4096 + w * 1024),
                                       16, 0, 0);
    }
  }

  // ---- Wave w stages elem w (f32 -> bf16, [s][q] transposed, swizzled) ----
  {
    const int s = lane;
    const float* xb = x + (bbase + w) * 4096;
    const unsigned sw = ((unsigned)(s & 7)) << 4;
    char* base = XsT + w * 8192 + s * 128;
    #pragma unroll
    for (int c = 0; c < 4; ++c) {               // 16 q per chunk
      unsigned int d[8];
      #pragma unroll
      for (int jj = 0; jj < 8; ++jj) {
        float a  = xb[(c * 16 + 2 * jj + 0) * 64 + s];
        float bq = xb[(c * 16 + 2 * jj + 1) * 64 + s];
        d[jj] = pkcvt(a, bq);
      }
      u32x4 v0 = {d[0], d[1], d[2], d[3]};
      u32x4 v1 = {d[4], d[5], d[6], d[7]};
      *(u32x4*)(base + (((unsigned)(c * 32)) ^ sw))      = v0;
      *(u32x4*)(base + (((unsigned)(c * 32 + 16)) ^ sw)) = v1;
    }
  }
  asm volatile("s_waitcnt vmcnt(0)" ::: "memory");
  __syncthreads();

  // ---- Hoist GEMM1 A-frags for both elems (loop-invariant): 16 ds_read_b128
  sh8 af[2][2][4];
  #pragma unroll
  for (int e = 0; e < 2; ++e) {
    const char* myX = XsT + (ep + e) * 8192;
    #pragma unroll
    for (int st = 0; st < 2; ++st)
      #pragma unroll
      for (int kq = 0; kq < 4; ++kq) {
        int srow = st * 32 + l31;
        unsigned boff = (unsigned)srow * 128 +
                        (((unsigned)(kq * 32 + h * 16)) ^ (((unsigned)(srow & 7)) << 4));
        af[e][st][kq] = *(const sh8*)(myX + boff);
      }
  }

  const fx16 zc = fzero16();
  fx16 accO[2][2];                 // [elem][nt]
  accO[0][0] = zc; accO[0][1] = zc;
  accO[1][0] = zc; accO[1][1] = zc;

  #pragma unroll 1
  for (int t2 = 0; t2 < 16; ++t2) {
    char* cur = WL + (t2 & 1) * 16384;

    // ---- issue stage of t2+1 into the other buffer (landed-by-barrier) ----
    if (t2 < 15) {
      char* dst = WL + ((t2 + 1) & 1) * 16384;
      const size_t toff = (size_t)(t2 + 1) * 8192;
      #pragma unroll
      for (int c = 0; c < 4; ++c) {
        const char* src = (c < 2) ? (w1c + toff + c * 4096)
                                  : (w2c + toff + (c - 2) * 4096);
        src += w * 1024 + lane * 16;
        __builtin_amdgcn_global_load_lds((const unsigned int*)src,
                                         (unsigned int*)(dst + c * 4096 + w * 1024),
                                         16, 0, 0);
      }
    }

    // ---- b1 frags from LDS (4 ds_read_b128) ----
    sh8 b1[4];
    #pragma unroll
    for (int kq = 0; kq < 4; ++kq)
      b1[kq] = *(const sh8*)(cur + (((mh * 4 + kq) * 64 + lane) << 4));

    // ---- G1 MERGED: 16 MFMA, 4 independent chains ----
    fx16 accY[2], accZ[2];
    __builtin_amdgcn_s_setprio(1);
    accY[0] = __builtin_amdgcn_mfma_f32_32x32x16_bf16(af[0][0][0], b1[0], zc, 0, 0, 0);
    accY[1] = __builtin_amdgcn_mfma_f32_32x32x16_bf16(af[0][1][0], b1[0], zc, 0, 0, 0);
    accZ[0] = __builtin_amdgcn_mfma_f32_32x32x16_bf16(af[1][0][0], b1[0], zc, 0, 0, 0);
    accZ[1] = __builtin_amdgcn_mfma_f32_32x32x16_bf16(af[1][1][0], b1[0], zc, 0, 0, 0);
    #pragma unroll
    for (int kq = 1; kq < 4; ++kq) {
      accY[0] = __builtin_amdgcn_mfma_f32_32x32x16_bf16(af[0][0][kq], b1[kq], accY[0], 0, 0, 0);
      accY[1] = __builtin_amdgcn_mfma_f32_32x32x16_bf16(af[0][1][kq], b1[kq], accY[1], 0, 0, 0);
      accZ[0] = __builtin_amdgcn_mfma_f32_32x32x16_bf16(af[1][0][kq], b1[kq], accZ[0], 0, 0, 0);
      accZ[1] = __builtin_amdgcn_mfma_f32_32x32x16_bf16(af[1][1][kq], b1[kq], accZ[1], 0, 0, 0);
    }
    __builtin_amdgcn_s_setprio(0);

    // ---- b2 frags from LDS (8 ds_read_b128; latency rides under packs) ----
    sh8 b2[2][4];
    #pragma unroll
    for (int nt = 0; nt < 2; ++nt)
      #pragma unroll
      for (int ks = 0; ks < 4; ++ks)
        b2[nt][ks] = *(const sh8*)(cur + 8192 + (((nt * 4 + ks) * 64 + lane) << 4));

    // ---- packs: e0 then e1 (32 cvt_pk total; sigma in W2) ----
    sh8 ga0[4], ga1[4];
    #pragma unroll
    for (int st = 0; st < 2; ++st) {
      fx16 Y = accY[st];
      union { u32x4 u; sh8 s8; } c0, c1;
      c0.u = (u32x4){pkcvt(Y[0], Y[1]),  pkcvt(Y[2], Y[3]),
                     pkcvt(Y[4], Y[5]),  pkcvt(Y[6], Y[7])};
      c1.u = (u32x4){pkcvt(Y[8], Y[9]),  pkcvt(Y[10], Y[11]),
                     pkcvt(Y[12], Y[13]), pkcvt(Y[14], Y[15])};
      ga0[st * 2 + 0] = c0.s8;
      ga0[st * 2 + 1] = c1.s8;
    }
    #pragma unroll
    for (int st = 0; st < 2; ++st) {
      fx16 Y = accZ[st];
      union { u32x4 u; sh8 s8; } c0, c1;
      c0.u = (u32x4){pkcvt(Y[0], Y[1]),  pkcvt(Y[2], Y[3]),
                     pkcvt(Y[4], Y[5]),  pkcvt(Y[6], Y[7])};
      c1.u = (u32x4){pkcvt(Y[8], Y[9]),  pkcvt(Y[10], Y[11]),
                     pkcvt(Y[12], Y[13]), pkcvt(Y[14], Y[15])};
      ga1[st * 2 + 0] = c0.s8;
      ga1[st * 2 + 1] = c1.s8;
    }

    // ---- G2 MERGED: 16 MFMA, 4 independent chains ----
    __builtin_amdgcn_s_setprio(1);
    #pragma unroll
    for (int ks = 0; ks < 4; ++ks) {
      accO[0][0] = __builtin_amdgcn_mfma_f32_32x32x16_bf16(ga0[ks], b2[0][ks], accO[0][0], 0, 0, 0);
      accO[0][1] = __builtin_amdgcn_mfma_f32_32x32x16_bf16(ga0[ks], b2[1][ks], accO[0][1], 0, 0, 0);
      accO[1][0] = __builtin_amdgcn_mfma_f32_32x32x16_bf16(ga1[ks], b2[0][ks], accO[1][0], 0, 0, 0);
      accO[1][1] = __builtin_amdgcn_mfma_f32_32x32x16_bf16(ga1[ks], b2[1][ks], accO[1][1], 0, 0, 0);
    }
    __builtin_amdgcn_s_setprio(0);

    // ---- single per-iter sync: stage landed, all reads of cur done ----
    asm volatile("s_waitcnt vmcnt(0)" ::: "memory");
    __syncthreads();
  }

  // ---- epilogue ----
  #pragma unroll
  for (int e = 0; e < 2; ++e) {
    float* ob = out + (bbase + ep + e) * 4096;
    #pragma unroll
    for (int nt = 0; nt < 2; ++nt) {
      #pragma unroll
      for (int reg = 0; reg < 16; ++reg) {
        int m = mh * 32 + (reg & 3) + 8 * (reg >> 2) + 4 * h;
        int n = nt * 32 + l31;
        int o = m * 64 + n;
        ob[o] = accO[e][nt][reg] + bias[o];
      }
    }
  }
}

// ---------------------------------------------------------------------------
extern "C" void kernel_launch(void* const* d_in, const int* in_sizes, int n_in,
                              void* d_out, int out_size, void* d_ws, size_t ws_size,
                              hipStream_t stream) {
  (void)n_in; (void)out_size; (void)ws_size;
  const float* x    = (const float*)d_in[0];
  const float* P0   = (const float*)d_in[1];
  const float* P1   = (const float*)d_in[2];
  const float* P2   = (const float*)d_in[3];
  const float* P3   = (const float*)d_in[4];
  const float* bias = (const float*)d_in[5];
  float* out = (float*)d_out;

  // ws: Qbuf f32[128*256] (128 KB) | W1 bf16[65536] (128 KB) | W2 bf16[65536] (128 KB)
  float* Qbuf = (float*)d_ws;
  unsigned short* W1 = (unsigned short*)((char*)d_ws + 131072);
  unsigned short* W2 = (unsigned short*)((char*)d_ws + 262144);

  k_cayley<<<8, 256, 0, stream>>>(P1, P2, Qbuf);
  k_build<<<512, 256, 0, stream>>>(P0, P3, Qbuf, W1, W2);

  int batch = in_sizes[0] / 4096;
  k_main<<<batch / 4, 256, 0, stream>>>(x, W1, W2, bias, out);
}